// Round 1
// baseline (693.948 us; speedup 1.0000x reference)
//
#include <hip/hip_runtime.h>
#include <math.h>

#define NB 16
#define NN 2048
#define NF 128
#define NH 128
#define NO 64

__device__ __forceinline__ float lrelu(float x) { return x > 0.f ? x : 0.2f * x; }

// K1: support[b*N+n][d] = sum_c x[b*N+n][c] * W[c][d]
__global__ __launch_bounds__(128) void k_support(const float* __restrict__ x,
                                                 const float* __restrict__ W,
                                                 float* __restrict__ supp) {
  const int row = blockIdx.x;
  const int d = threadIdx.x;
  __shared__ float xs[NF];
  xs[d] = x[(size_t)row * NF + d];
  __syncthreads();
  float a0 = 0.f, a1 = 0.f;
#pragma unroll 16
  for (int k = 0; k < NF; k += 2) {
    a0 = fmaf(xs[k], W[k * NH + d], a0);
    a1 = fmaf(xs[k + 1], W[(k + 1) * NH + d], a1);
  }
  supp[(size_t)row * NH + d] = a0 + a1;
}

// K2: h[b][n][d] = sum_m adj[n][m] * supp[b][m][d] + bias[d]
// Viewed as C[n][c] with c = b*128+d; 64x64 tile, K-tile 32, 4x4 per thread.
__global__ __launch_bounds__(256) void k_gcn(const float* __restrict__ adj,
                                             const float* __restrict__ supp,
                                             const float* __restrict__ bias,
                                             float* __restrict__ hbuf) {
  const int n0 = blockIdx.y * 64;
  const int c0 = blockIdx.x * 64;
  const int bb = c0 >> 7;
  const int d0 = c0 & 127;
  const int t = threadIdx.x;
  const int tr = t >> 4, tc = t & 15;
  __shared__ float As[64][36];  // adj[n0+r][m0+k], row-major, pad 4 (16B-aligned rows)
  __shared__ float Bs[32][64];  // supp[bb][m0+k][d0+j], k-major
  float acc[4][4] = {};
  const int lx = t & 31, lz = t >> 5;
  const int bj = t & 63, bk = t >> 6;
  for (int m0 = 0; m0 < NN; m0 += 32) {
    __syncthreads();
#pragma unroll
    for (int r = lz; r < 64; r += 8)
      As[r][lx] = adj[(size_t)(n0 + r) * NN + m0 + lx];
#pragma unroll
    for (int k = bk; k < 32; k += 4)
      Bs[k][bj] = supp[((size_t)bb * NN + m0 + k) * NH + d0 + bj];
    __syncthreads();
#pragma unroll
    for (int kq = 0; kq < 32; kq += 4) {
      const float4 b0 = *(const float4*)&Bs[kq + 0][tc * 4];
      const float4 b1 = *(const float4*)&Bs[kq + 1][tc * 4];
      const float4 b2 = *(const float4*)&Bs[kq + 2][tc * 4];
      const float4 b3 = *(const float4*)&Bs[kq + 3][tc * 4];
#pragma unroll
      for (int ii = 0; ii < 4; ++ii) {
        const float4 a = *(const float4*)&As[tr * 4 + ii][kq];
        acc[ii][0] = fmaf(a.x, b0.x, fmaf(a.y, b1.x, fmaf(a.z, b2.x, fmaf(a.w, b3.x, acc[ii][0]))));
        acc[ii][1] = fmaf(a.x, b0.y, fmaf(a.y, b1.y, fmaf(a.z, b2.y, fmaf(a.w, b3.y, acc[ii][1]))));
        acc[ii][2] = fmaf(a.x, b0.z, fmaf(a.y, b1.z, fmaf(a.z, b2.z, fmaf(a.w, b3.z, acc[ii][2]))));
        acc[ii][3] = fmaf(a.x, b0.w, fmaf(a.y, b1.w, fmaf(a.z, b2.w, fmaf(a.w, b3.w, acc[ii][3]))));
      }
    }
  }
  const float4 bv = *(const float4*)&bias[d0 + tc * 4];
#pragma unroll
  for (int ii = 0; ii < 4; ++ii) {
    const int gn = n0 + tr * 4 + ii;
    float4 o;
    o.x = acc[ii][0] + bv.x;
    o.y = acc[ii][1] + bv.y;
    o.z = acc[ii][2] + bv.z;
    o.w = acc[ii][3] + bv.w;
    *(float4*)&hbuf[((size_t)bb * NN + gn) * NH + d0 + tc * 4] = o;
  }
}

// K3a: per-128-row partial sums/sumsq per channel
__global__ __launch_bounds__(256) void k_bnstat1(const float* __restrict__ hbuf,
                                                 float* __restrict__ psum,
                                                 float* __restrict__ psq) {
  const int blk = blockIdx.x;  // 256 blocks x 128 rows
  const int t = threadIdx.x;
  const int d = t & 127;
  const int rh = t >> 7;
  float s = 0.f, q = 0.f;
  for (int r = rh; r < 128; r += 2) {
    const float v = hbuf[((size_t)blk * 128 + r) * NH + d];
    s += v;
    q = fmaf(v, v, q);
  }
  __shared__ float ls[2][128], lq[2][128];
  ls[rh][d] = s;
  lq[rh][d] = q;
  __syncthreads();
  if (t < 128) {
    psum[blk * 128 + t] = ls[0][t] + ls[1][t];
    psq[blk * 128 + t] = lq[0][t] + lq[1][t];
  }
}

// K3b: finalize mean/var -> scale/shift
__global__ __launch_bounds__(1024) void k_bnstat2(const float* __restrict__ psum,
                                                  const float* __restrict__ psq,
                                                  const float* __restrict__ gamma,
                                                  const float* __restrict__ beta,
                                                  float* __restrict__ scale,
                                                  float* __restrict__ shift) {
  const int t = threadIdx.x;
  const int d = t & 127;
  const int g = t >> 7;  // 0..7
  float s = 0.f, q = 0.f;
  for (int i = g; i < 256; i += 8) {
    s += psum[i * 128 + d];
    q += psq[i * 128 + d];
  }
  __shared__ float ls[8][128], lq[8][128];
  ls[g][d] = s;
  lq[g][d] = q;
  __syncthreads();
  if (t < 128) {
    s = 0.f;
    q = 0.f;
#pragma unroll
    for (int i = 0; i < 8; ++i) {
      s += ls[i][t];
      q += lq[i][t];
    }
    const float inv = 1.f / (float)(NB * NN);
    const float mean = s * inv;
    const float var = q * inv - mean * mean;
    const float sc = gamma[t] * rsqrtf(var + 1e-5f);
    scale[t] = sc;
    shift[t] = beta[t] - mean * sc;
  }
}

// K4: hp[row][c] = sum_k relu(bn(h[row][k])) * gatW[k][c]
__global__ __launch_bounds__(256) void k_hp(const float* __restrict__ hbuf,
                                            const float* __restrict__ scale,
                                            const float* __restrict__ shift,
                                            const float* __restrict__ gatW,
                                            float* __restrict__ hp) {
  const int t = threadIdx.x;
  const size_t row0 = (size_t)blockIdx.x * 4;
  __shared__ float hs[4][NH];
#pragma unroll
  for (int i = 0; i < 2; ++i) {
    const int idx = t + i * 256;
    const int rl = idx >> 7, k = idx & 127;
    const float v = fmaf(hbuf[(row0 + rl) * NH + k], scale[k], shift[k]);
    hs[rl][k] = fmaxf(v, 0.f);
  }
  __syncthreads();
  const int rl = t >> 6, c = t & 63;
  float a0 = 0.f, a1 = 0.f;
#pragma unroll 16
  for (int k = 0; k < NH; k += 2) {
    a0 = fmaf(hs[rl][k], gatW[k * NO + c], a0);
    a1 = fmaf(hs[rl][k + 1], gatW[(k + 1) * NO + c], a1);
  }
  hp[(row0 + rl) * NO + c] = a0 + a1;
}

// K5 (pass A): per row n of batch bb: M[n] = max_m lrelu(hp[n].hp[m]);
//              D[n] = sum_m exp(E-M[n])  (flash-style running update).
// By symmetry of E these equal the softmax-axis (column) max/denominator.
__global__ __launch_bounds__(256) void k_passA(const float* __restrict__ hp,
                                               float* __restrict__ Mbuf,
                                               float* __restrict__ Dbuf) {
  const int bb = blockIdx.x >> 5;
  const int n0 = (blockIdx.x & 31) * 64;
  const int t = threadIdx.x;
  const int tr = t >> 4, tc = t & 15;
  __shared__ float Rt[64][68];
  __shared__ float Ct[64][68];
#pragma unroll
  for (int pass = 0; pass < 4; ++pass) {
    const int id = pass * 256 + t;
    const int r = id >> 4, c4 = (id & 15) * 4;
    *(float4*)&Rt[r][c4] = *(const float4*)&hp[((size_t)bb * NN + n0 + r) * NO + c4];
  }
  float M[4], S[4];
#pragma unroll
  for (int ii = 0; ii < 4; ++ii) {
    M[ii] = -INFINITY;
    S[ii] = 0.f;
  }
  for (int m0 = 0; m0 < NN; m0 += 64) {
    __syncthreads();
#pragma unroll
    for (int pass = 0; pass < 4; ++pass) {
      const int id = pass * 256 + t;
      const int r = id >> 4, c4 = (id & 15) * 4;
      *(float4*)&Ct[r][c4] = *(const float4*)&hp[((size_t)bb * NN + m0 + r) * NO + c4];
    }
    __syncthreads();
    float acc[4][4] = {};
#pragma unroll
    for (int kq = 0; kq < NO; kq += 4) {
      const float4 c0 = *(const float4*)&Ct[tc][kq];
      const float4 c1 = *(const float4*)&Ct[tc + 16][kq];
      const float4 c2 = *(const float4*)&Ct[tc + 32][kq];
      const float4 c3 = *(const float4*)&Ct[tc + 48][kq];
#pragma unroll
      for (int ii = 0; ii < 4; ++ii) {
        const float4 a = *(const float4*)&Rt[tr * 4 + ii][kq];
        acc[ii][0] = fmaf(a.x, c0.x, fmaf(a.y, c0.y, fmaf(a.z, c0.z, fmaf(a.w, c0.w, acc[ii][0]))));
        acc[ii][1] = fmaf(a.x, c1.x, fmaf(a.y, c1.y, fmaf(a.z, c1.z, fmaf(a.w, c1.w, acc[ii][1]))));
        acc[ii][2] = fmaf(a.x, c2.x, fmaf(a.y, c2.y, fmaf(a.z, c2.z, fmaf(a.w, c2.w, acc[ii][2]))));
        acc[ii][3] = fmaf(a.x, c3.x, fmaf(a.y, c3.y, fmaf(a.z, c3.z, fmaf(a.w, c3.w, acc[ii][3]))));
      }
    }
#pragma unroll
    for (int ii = 0; ii < 4; ++ii) {
      const float v0 = lrelu(acc[ii][0]);
      const float v1 = lrelu(acc[ii][1]);
      const float v2 = lrelu(acc[ii][2]);
      const float v3 = lrelu(acc[ii][3]);
      float tmax = fmaxf(fmaxf(v0, v1), fmaxf(v2, v3));
#pragma unroll
      for (int w = 1; w < 16; w <<= 1) tmax = fmaxf(tmax, __shfl_xor(tmax, w));
      const float newM = fmaxf(M[ii], tmax);
      float p = __expf(v0 - newM) + __expf(v1 - newM) + __expf(v2 - newM) + __expf(v3 - newM);
#pragma unroll
      for (int w = 1; w < 16; w <<= 1) p += __shfl_xor(p, w);
      S[ii] = fmaf(S[ii], __expf(M[ii] - newM), p);
      M[ii] = newM;
    }
  }
  if (tc == 0) {
#pragma unroll
    for (int ii = 0; ii < 4; ++ii) {
      Mbuf[bb * NN + n0 + tr * 4 + ii] = M[ii];
      Dbuf[bb * NN + n0 + tr * 4 + ii] = S[ii];
    }
  }
}

// K6 (pass B): S[n] = sum_m exp(E[n][m]-M[m]) / D[m]; out = hp * S
__global__ __launch_bounds__(256) void k_passB(const float* __restrict__ hp,
                                               const float* __restrict__ Mbuf,
                                               const float* __restrict__ Dbuf,
                                               float* __restrict__ out) {
  const int bb = blockIdx.x >> 5;
  const int n0 = (blockIdx.x & 31) * 64;
  const int t = threadIdx.x;
  const int tr = t >> 4, tc = t & 15;
  __shared__ float Rt[64][68];
  __shared__ float Ct[64][68];
  __shared__ float Mv[64], iDv[64];
#pragma unroll
  for (int pass = 0; pass < 4; ++pass) {
    const int id = pass * 256 + t;
    const int r = id >> 4, c4 = (id & 15) * 4;
    *(float4*)&Rt[r][c4] = *(const float4*)&hp[((size_t)bb * NN + n0 + r) * NO + c4];
  }
  float S[4] = {0.f, 0.f, 0.f, 0.f};
  for (int m0 = 0; m0 < NN; m0 += 64) {
    __syncthreads();
#pragma unroll
    for (int pass = 0; pass < 4; ++pass) {
      const int id = pass * 256 + t;
      const int r = id >> 4, c4 = (id & 15) * 4;
      *(float4*)&Ct[r][c4] = *(const float4*)&hp[((size_t)bb * NN + m0 + r) * NO + c4];
    }
    if (t < 64) {
      Mv[t] = Mbuf[bb * NN + m0 + t];
      iDv[t] = 1.f / Dbuf[bb * NN + m0 + t];
    }
    __syncthreads();
    float acc[4][4] = {};
#pragma unroll
    for (int kq = 0; kq < NO; kq += 4) {
      const float4 c0 = *(const float4*)&Ct[tc][kq];
      const float4 c1 = *(const float4*)&Ct[tc + 16][kq];
      const float4 c2 = *(const float4*)&Ct[tc + 32][kq];
      const float4 c3 = *(const float4*)&Ct[tc + 48][kq];
#pragma unroll
      for (int ii = 0; ii < 4; ++ii) {
        const float4 a = *(const float4*)&Rt[tr * 4 + ii][kq];
        acc[ii][0] = fmaf(a.x, c0.x, fmaf(a.y, c0.y, fmaf(a.z, c0.z, fmaf(a.w, c0.w, acc[ii][0]))));
        acc[ii][1] = fmaf(a.x, c1.x, fmaf(a.y, c1.y, fmaf(a.z, c1.z, fmaf(a.w, c1.w, acc[ii][1]))));
        acc[ii][2] = fmaf(a.x, c2.x, fmaf(a.y, c2.y, fmaf(a.z, c2.z, fmaf(a.w, c2.w, acc[ii][2]))));
        acc[ii][3] = fmaf(a.x, c3.x, fmaf(a.y, c3.y, fmaf(a.z, c3.z, fmaf(a.w, c3.w, acc[ii][3]))));
      }
    }
#pragma unroll
    for (int ii = 0; ii < 4; ++ii) {
      float p = __expf(lrelu(acc[ii][0]) - Mv[tc]) * iDv[tc];
      p = fmaf(__expf(lrelu(acc[ii][1]) - Mv[tc + 16]), iDv[tc + 16], p);
      p = fmaf(__expf(lrelu(acc[ii][2]) - Mv[tc + 32]), iDv[tc + 32], p);
      p = fmaf(__expf(lrelu(acc[ii][3]) - Mv[tc + 48]), iDv[tc + 48], p);
#pragma unroll
      for (int w = 1; w < 16; w <<= 1) p += __shfl_xor(p, w);
      S[ii] += p;
    }
  }
#pragma unroll
  for (int ii = 0; ii < 4; ++ii) {
    const size_t base = ((size_t)bb * NN + n0 + tr * 4 + ii) * NO + tc * 4;
    const float4 v = *(const float4*)&hp[base];
    float4 o;
    o.x = v.x * S[ii];
    o.y = v.y * S[ii];
    o.z = v.z * S[ii];
    o.w = v.w * S[ii];
    *(float4*)&out[base] = o;
  }
}

extern "C" void kernel_launch(void* const* d_in, const int* in_sizes, int n_in,
                              void* d_out, int out_size, void* d_ws, size_t ws_size,
                              hipStream_t stream) {
  const float* x = (const float*)d_in[0];
  // d_in[1] = adj (unused by the reference)
  const float* adj_gcn = (const float*)d_in[2];
  const float* gcn_w = (const float*)d_in[3];
  const float* gcn_b = (const float*)d_in[4];
  const float* gamma = (const float*)d_in[5];
  const float* beta = (const float*)d_in[6];
  const float* gat_w = (const float*)d_in[7];
  float* out = (float*)d_out;
  float* ws = (float*)d_ws;

  // workspace layout (floats):
  float* supp = ws;                    // [0, 4194304)   16MB (dead after k_gcn)
  float* hbuf = ws + 4194304;          // [4194304, 8388608) 16MB
  float* hp = ws;                      // [0, 2097152)   8MB (aliases dead supp)
  float* Mbuf = ws + 2097152;          // 32768
  float* Dbuf = ws + 2097152 + 32768;  // 32768
  float* psum = ws + 8388608;          // 32768
  float* psq = psum + 32768;           // 32768
  float* scale = psq + 32768;          // 128
  float* shift = scale + 128;          // 128

  k_support<<<dim3(NB * NN), dim3(128), 0, stream>>>(x, gcn_w, supp);
  k_gcn<<<dim3(32, 32), dim3(256), 0, stream>>>(adj_gcn, supp, gcn_b, hbuf);
  k_bnstat1<<<dim3(256), dim3(256), 0, stream>>>(hbuf, psum, psq);
  k_bnstat2<<<dim3(1), dim3(1024), 0, stream>>>(psum, psq, gamma, beta, scale, shift);
  k_hp<<<dim3(NB * NN / 4), dim3(256), 0, stream>>>(hbuf, scale, shift, gat_w, hp);
  k_passA<<<dim3(NB * 32), dim3(256), 0, stream>>>(hp, Mbuf, Dbuf);
  k_passB<<<dim3(NB * 32), dim3(256), 0, stream>>>(hp, Mbuf, Dbuf, out);
}

// Round 2
// 246.743 us; speedup vs baseline: 2.8124x; 2.8124x over previous
//
#include <hip/hip_runtime.h>
#include <math.h>

#define NB 16
#define NN 2048
#define NF 128
#define NH 128
#define NO 64

typedef short bf16x8 __attribute__((ext_vector_type(8)));
typedef float f32x4 __attribute__((ext_vector_type(4)));
typedef unsigned short u16;
typedef unsigned int u32;

__device__ __forceinline__ u16 f2bf(float f) {
  u32 u = __builtin_bit_cast(u32, f);
  return (u16)((u + 0x7fffu + ((u >> 16) & 1u)) >> 16);
}
__device__ __forceinline__ float bf2f(u16 h) {
  u32 u = ((u32)h) << 16;
  return __builtin_bit_cast(float, u);
}
__device__ __forceinline__ float lrelu(float x) { return x > 0.f ? x : 0.2f * x; }

__device__ __forceinline__ void gload16(const void* g, void* l) {
  __builtin_amdgcn_global_load_lds((const __attribute__((address_space(1))) void*)g,
                                   (__attribute__((address_space(3))) void*)l, 16, 0, 0);
}
__device__ __forceinline__ f32x4 mfma16(bf16x8 a, bf16x8 b, f32x4 c) {
  return __builtin_amdgcn_mfma_f32_16x16x32_bf16(a, b, c, 0, 0, 0);
}

// ---------------- K1: support[b*N+m][d] = sum_c x[..][c] * W[c][d] (fp32) ----
__global__ __launch_bounds__(128) void k_support(const float* __restrict__ x,
                                                 const float* __restrict__ W,
                                                 float* __restrict__ supp) {
  const int row = blockIdx.x;
  const int d = threadIdx.x;
  __shared__ float xs[NF];
  xs[d] = x[(size_t)row * NF + d];
  __syncthreads();
  float a0 = 0.f, a1 = 0.f;
#pragma unroll 16
  for (int k = 0; k < NF; k += 2) {
    a0 = fmaf(xs[k], W[k * NH + d], a0);
    a1 = fmaf(xs[k + 1], W[(k + 1) * NH + d], a1);
  }
  supp[(size_t)row * NH + d] = a0 + a1;
}

// ---------------- K2: transpose-cast supp -> suppT[b*128+d][m] bf16 ----------
__global__ __launch_bounds__(256) void k_tcast(const float* __restrict__ supp,
                                               u16* __restrict__ suppT) {
  const int r0 = blockIdx.x * 64;  // global row = b*2048 + m
  const int d0 = blockIdx.y * 64;
  __shared__ u16 ts[64][72];
  const int t = threadIdx.x;
#pragma unroll
  for (int k = 0; k < 4; ++k) {
    int s = t + k * 256;  // 1024 float4 slots
    int row = s >> 4, j4 = (s & 15) * 4;
    float4 v = *(const float4*)&supp[(size_t)(r0 + row) * NH + d0 + j4];
    ts[row][j4 + 0] = f2bf(v.x);
    ts[row][j4 + 1] = f2bf(v.y);
    ts[row][j4 + 2] = f2bf(v.z);
    ts[row][j4 + 3] = f2bf(v.w);
  }
  __syncthreads();
  const int b = r0 >> 11, m0 = r0 & 2047;
#pragma unroll
  for (int k = 0; k < 8; ++k) {
    int s = t + k * 256;  // 2048 ushort2 slots: d(64) x m2(32)
    int d = s >> 5, m2 = (s & 31) * 2;
    u32 pk = (u32)ts[m2][d] | ((u32)ts[m2 + 1][d] << 16);
    *(u32*)&suppT[((size_t)(b * 128 + d0 + d)) * 2048 + m0 + m2] = pk;
  }
}

// ---------------- K3: cast adj fp32 -> bf16 (row-major) ----------------------
__global__ __launch_bounds__(256) void k_cast_adj(const float* __restrict__ a,
                                                  u16* __restrict__ o) {
  const int i = blockIdx.x * 256 + threadIdx.x;
#pragma unroll
  for (int k = 0; k < 4; ++k) {
    int v4 = i + k * 262144;  // 1,048,576 float4s total
    float4 f = *(const float4*)&a[(size_t)v4 * 4];
    u32 r0 = (u32)f2bf(f.x) | ((u32)f2bf(f.y) << 16);
    u32 r1 = (u32)f2bf(f.z) | ((u32)f2bf(f.w) << 16);
    uint2 r;
    r.x = r0;
    r.y = r1;
    *(uint2*)&o[(size_t)v4 * 4] = r;
  }
}

// ---------------- K4: transpose gat_W -> gWT[c][k] fp32 ----------------------
__global__ __launch_bounds__(256) void k_wt(const float* __restrict__ gw,
                                            float* __restrict__ gWT) {
  const int t = threadIdx.x;
  const int c = t & 63, kq = t >> 6;
  for (int k = kq * 32; k < kq * 32 + 32; ++k) gWT[c * 128 + k] = gw[k * 64 + c];
}

// ---------------- K5: GCN GEMM (bf16 MFMA): h = adj @ supp + bias ------------
// BM=64 (n), BN=128 (d), BK=32. grid (32 ntiles, 16 b). 4 waves, wave-tile 32x64.
__global__ __launch_bounds__(256) void k_gcn(const u16* __restrict__ adjbf,
                                             const u16* __restrict__ suppT,
                                             const float* __restrict__ bias,
                                             float* __restrict__ h) {
  const int n0 = blockIdx.x * 64;
  const int b = blockIdx.y;
  const int t = threadIdx.x;
  const int w = t >> 6, l = t & 63;
  const int wm = w >> 1, wn = w & 1;
  __shared__ __align__(16) u16 As[2][2048];  // [4 kblk][64 row][8]
  __shared__ __align__(16) u16 Bs[2][4096];  // [4 kblk][128 d][8]

  f32x4 acc[2][4];
#pragma unroll
  for (int mf = 0; mf < 2; ++mf)
#pragma unroll
    for (int nf = 0; nf < 4; ++nf) {
      acc[mf][nf][0] = 0.f; acc[mf][nf][1] = 0.f;
      acc[mf][nf][2] = 0.f; acc[mf][nf][3] = 0.f;
    }

#define GCN_STAGE(buf, k0)                                                      \
  {                                                                             \
    _Pragma("unroll") for (int i = 0; i < 3; ++i) {                             \
      int idx = w * 3 + i;                                                      \
      if (idx < 4) {                                                            \
        int slot = idx * 64 + l;                                                \
        int kb = slot >> 6, row = slot & 63;                                    \
        gload16(adjbf + (size_t)(n0 + row) * 2048 + (k0) + kb * 8,              \
                &As[buf][idx * 512]);                                           \
      } else {                                                                  \
        int slot = (idx - 4) * 64 + l;                                          \
        int kb = slot >> 7, d = slot & 127;                                     \
        gload16(suppT + (((size_t)(b * 128 + d)) << 11) + (k0) + kb * 8,        \
                &Bs[buf][(idx - 4) * 512]);                                     \
      }                                                                         \
    }                                                                           \
  }

  GCN_STAGE(0, 0);
  __syncthreads();
  const int lg = l >> 4, lr = l & 15;
  for (int ks = 0; ks < 64; ++ks) {
    const int cur = ks & 1;
    if (ks + 1 < 64) GCN_STAGE(cur ^ 1, (ks + 1) * 32);
    bf16x8 a0 = *(const bf16x8*)&As[cur][(lg * 64 + wm * 32 + 0 + lr) * 8];
    bf16x8 a1 = *(const bf16x8*)&As[cur][(lg * 64 + wm * 32 + 16 + lr) * 8];
    bf16x8 b0 = *(const bf16x8*)&Bs[cur][(lg * 128 + wn * 64 + 0 + lr) * 8];
    bf16x8 b1 = *(const bf16x8*)&Bs[cur][(lg * 128 + wn * 64 + 16 + lr) * 8];
    bf16x8 b2 = *(const bf16x8*)&Bs[cur][(lg * 128 + wn * 64 + 32 + lr) * 8];
    bf16x8 b3 = *(const bf16x8*)&Bs[cur][(lg * 128 + wn * 64 + 48 + lr) * 8];
    acc[0][0] = mfma16(a0, b0, acc[0][0]);
    acc[0][1] = mfma16(a0, b1, acc[0][1]);
    acc[0][2] = mfma16(a0, b2, acc[0][2]);
    acc[0][3] = mfma16(a0, b3, acc[0][3]);
    acc[1][0] = mfma16(a1, b0, acc[1][0]);
    acc[1][1] = mfma16(a1, b1, acc[1][1]);
    acc[1][2] = mfma16(a1, b2, acc[1][2]);
    acc[1][3] = mfma16(a1, b3, acc[1][3]);
    __syncthreads();
  }
#undef GCN_STAGE
  // epilogue: D frag col=lane&15, row=(lane>>4)*4+reg
#pragma unroll
  for (int nf = 0; nf < 4; ++nf) {
    const int d = wn * 64 + nf * 16 + lr;
    const float bv = bias[d];
#pragma unroll
    for (int mf = 0; mf < 2; ++mf) {
#pragma unroll
      for (int r = 0; r < 4; ++r) {
        const int row = n0 + wm * 32 + mf * 16 + lg * 4 + r;
        h[((size_t)(b * NN + row)) * NH + d] = acc[mf][nf][r] + bv;
      }
    }
  }
}

// ---------------- BN stats ---------------------------------------------------
__global__ __launch_bounds__(256) void k_bnstat1(const float* __restrict__ h,
                                                 float* __restrict__ psum,
                                                 float* __restrict__ psq) {
  const int blk = blockIdx.x;
  const int t = threadIdx.x;
  const int d = t & 127;
  const int rh = t >> 7;
  float s = 0.f, q = 0.f;
  for (int r = rh; r < 128; r += 2) {
    const float v = h[((size_t)blk * 128 + r) * NH + d];
    s += v;
    q = fmaf(v, v, q);
  }
  __shared__ float ls[2][128], lq[2][128];
  ls[rh][d] = s;
  lq[rh][d] = q;
  __syncthreads();
  if (t < 128) {
    psum[blk * 128 + t] = ls[0][t] + ls[1][t];
    psq[blk * 128 + t] = lq[0][t] + lq[1][t];
  }
}

__global__ __launch_bounds__(1024) void k_bnstat2(const float* __restrict__ psum,
                                                  const float* __restrict__ psq,
                                                  const float* __restrict__ gamma,
                                                  const float* __restrict__ beta,
                                                  float* __restrict__ scale,
                                                  float* __restrict__ shift) {
  const int t = threadIdx.x;
  const int d = t & 127;
  const int g = t >> 7;
  float s = 0.f, q = 0.f;
  for (int i = g; i < 256; i += 8) {
    s += psum[i * 128 + d];
    q += psq[i * 128 + d];
  }
  __shared__ float ls[8][128], lq[8][128];
  ls[g][d] = s;
  lq[g][d] = q;
  __syncthreads();
  if (t < 128) {
    s = 0.f;
    q = 0.f;
#pragma unroll
    for (int i = 0; i < 8; ++i) {
      s += ls[i][t];
      q += lq[i][t];
    }
    const float inv = 1.f / (float)(NB * NN);
    const float mean = s * inv;
    const float var = q * inv - mean * mean;
    const float sc = gamma[t] * rsqrtf(var + 1e-5f);
    scale[t] = sc;
    shift[t] = beta[t] - mean * sc;
  }
}

// ---------------- K6: hp = relu(bn(h)) @ gat_W, written pre-swizzled bf16 ----
// hp_sw layout per 64-row tile: [8 kblk][64 row][8] bf16 (4096 elems contiguous)
__global__ __launch_bounds__(256) void k_hp(const float* __restrict__ h,
                                            const float* __restrict__ scale,
                                            const float* __restrict__ shift,
                                            const float* __restrict__ gWT,
                                            u16* __restrict__ hp_sw) {
  const int row0 = blockIdx.x * 64;
  __shared__ float hs[64][132];
  __shared__ __align__(16) u16 hos[64][72];
  const int t = threadIdx.x;
#pragma unroll
  for (int k = 0; k < 8; ++k) {
    int s = t + k * 256;  // 2048 float4 slots
    int row = s >> 5, c4 = (s & 31) * 4;
    float4 v = *(const float4*)&h[(size_t)(row0 + row) * NH + c4];
    float4 sc = *(const float4*)&scale[c4];
    float4 sh = *(const float4*)&shift[c4];
    hs[row][c4 + 0] = fmaxf(fmaf(v.x, sc.x, sh.x), 0.f);
    hs[row][c4 + 1] = fmaxf(fmaf(v.y, sc.y, sh.y), 0.f);
    hs[row][c4 + 2] = fmaxf(fmaf(v.z, sc.z, sh.z), 0.f);
    hs[row][c4 + 3] = fmaxf(fmaf(v.w, sc.w, sh.w), 0.f);
  }
  __syncthreads();
  const int c = t & 63, q = t >> 6;
  float acc[16];
#pragma unroll
  for (int r = 0; r < 16; ++r) acc[r] = 0.f;
  for (int c4 = 0; c4 < 32; ++c4) {
    const float4 wv = *(const float4*)&gWT[c * 128 + c4 * 4];
#pragma unroll
    for (int r = 0; r < 16; ++r) {
      const float4 hv = *(const float4*)&hs[q * 16 + r][c4 * 4];
      acc[r] = fmaf(hv.x, wv.x, fmaf(hv.y, wv.y, fmaf(hv.z, wv.z, fmaf(hv.w, wv.w, acc[r]))));
    }
  }
#pragma unroll
  for (int r = 0; r < 16; ++r) hos[q * 16 + r][c] = f2bf(acc[r]);
  __syncthreads();
  const size_t tbase = (size_t)blockIdx.x * 4096;
#pragma unroll
  for (int k = 0; k < 2; ++k) {
    int s = t + k * 256;  // 512 16B slots
    int kb = s >> 6, r6 = s & 63;
    uint2 lo = *(const uint2*)&hos[r6][kb * 8];
    uint2 hi = *(const uint2*)&hos[r6][kb * 8 + 4];
    uint4 o;
    o.x = lo.x; o.y = lo.y; o.z = hi.x; o.w = hi.y;
    *(uint4*)&hp_sw[tbase + kb * 512 + r6 * 8] = o;
  }
}

// ---------------- K7: attn pass A: M[n], 1/D[n] (row = col by symmetry) ------
__global__ __launch_bounds__(256) void k_attnA(const u16* __restrict__ hp_sw,
                                               float* __restrict__ Mbuf,
                                               float* __restrict__ iDbuf) {
  const int b = blockIdx.x >> 5;
  const int n0 = (blockIdx.x & 31) << 6;
  const int t = threadIdx.x, w = t >> 6, l = t & 63;
  const int lg = l >> 4, lr = l & 15;
  __shared__ __align__(16) u16 Rs[4096];
  __shared__ __align__(16) u16 Cs[2][4096];

  const int tileR = b * 32 + (n0 >> 6);
#pragma unroll
  for (int i = 0; i < 2; ++i) {
    int idx = w * 2 + i;
    gload16(hp_sw + (size_t)tileR * 4096 + (idx * 64 + l) * 8, &Rs[idx * 512]);
  }
#pragma unroll
  for (int i = 0; i < 2; ++i) {
    int idx = w * 2 + i;
    gload16(hp_sw + (size_t)(b * 32) * 4096 + (idx * 64 + l) * 8, &Cs[0][idx * 512]);
  }
  __syncthreads();
  const bf16x8 bq0 = *(const bf16x8*)&Rs[((lg) * 64 + (w << 4) + lr) * 8];
  const bf16x8 bq1 = *(const bf16x8*)&Rs[((lg + 4) * 64 + (w << 4) + lr) * 8];
  float M = -3.4e38f, S = 0.f;
  for (int mt = 0; mt < 32; ++mt) {
    const int cur = mt & 1;
    if (mt + 1 < 32) {
#pragma unroll
      for (int i = 0; i < 2; ++i) {
        int idx = w * 2 + i;
        gload16(hp_sw + (size_t)(b * 32 + mt + 1) * 4096 + (idx * 64 + l) * 8,
                &Cs[cur ^ 1][idx * 512]);
      }
    }
    f32x4 e[4];
#pragma unroll
    for (int mf = 0; mf < 4; ++mf) {
      bf16x8 a0 = *(const bf16x8*)&Cs[cur][((lg) * 64 + mf * 16 + lr) * 8];
      bf16x8 a1 = *(const bf16x8*)&Cs[cur][((lg + 4) * 64 + mf * 16 + lr) * 8];
      f32x4 z;
      z[0] = 0.f; z[1] = 0.f; z[2] = 0.f; z[3] = 0.f;
      z = mfma16(a0, bq0, z);
      z = mfma16(a1, bq1, z);
      e[mf] = z;
    }
    float vv[4][4];
    float tmax = -3.4e38f;
#pragma unroll
    for (int mf = 0; mf < 4; ++mf)
#pragma unroll
      for (int r = 0; r < 4; ++r) {
        float v = lrelu(e[mf][r]);
        vv[mf][r] = v;
        tmax = fmaxf(tmax, v);
      }
    tmax = fmaxf(tmax, __shfl_xor(tmax, 16));
    tmax = fmaxf(tmax, __shfl_xor(tmax, 32));
    const float newM = fmaxf(M, tmax);
    float p = 0.f;
#pragma unroll
    for (int mf = 0; mf < 4; ++mf)
#pragma unroll
      for (int r = 0; r < 4; ++r) p += __expf(vv[mf][r] - newM);
    p += __shfl_xor(p, 16);
    p += __shfl_xor(p, 32);
    S = S * __expf(M - newM) + p;
    M = newM;
    __syncthreads();
  }
  if (l < 16) {
    Mbuf[b * NN + n0 + (w << 4) + l] = M;
    iDbuf[b * NN + n0 + (w << 4) + l] = 1.f / S;
  }
}

// ---------------- K8: attn pass B: S[n] = sum_m exp(E-M[m])/D[m]; out=hp*S ---
__global__ __launch_bounds__(256) void k_attnB(const u16* __restrict__ hp_sw,
                                               const float* __restrict__ Mbuf,
                                               const float* __restrict__ iDbuf,
                                               float* __restrict__ out) {
  const int b = blockIdx.x >> 5;
  const int n0 = (blockIdx.x & 31) << 6;
  const int t = threadIdx.x, w = t >> 6, l = t & 63;
  const int lg = l >> 4, lr = l & 15;
  __shared__ __align__(16) u16 Rs[4096];
  __shared__ __align__(16) u16 Cs[2][4096];
  __shared__ __align__(16) float Mv[2][64], Dv[2][64];
  __shared__ float Sv[64];

  const int tileR = b * 32 + (n0 >> 6);
#pragma unroll
  for (int i = 0; i < 2; ++i) {
    int idx = w * 2 + i;
    gload16(hp_sw + (size_t)tileR * 4096 + (idx * 64 + l) * 8, &Rs[idx * 512]);
  }
#pragma unroll
  for (int i = 0; i < 2; ++i) {
    int idx = w * 2 + i;
    gload16(hp_sw + (size_t)(b * 32) * 4096 + (idx * 64 + l) * 8, &Cs[0][idx * 512]);
  }
  if (t < 64) {
    Mv[0][t] = Mbuf[b * NN + t];
    Dv[0][t] = iDbuf[b * NN + t];
  }
  __syncthreads();
  const bf16x8 bq0 = *(const bf16x8*)&Rs[((lg) * 64 + (w << 4) + lr) * 8];
  const bf16x8 bq1 = *(const bf16x8*)&Rs[((lg + 4) * 64 + (w << 4) + lr) * 8];
  float S = 0.f;
  for (int mt = 0; mt < 32; ++mt) {
    const int cur = mt & 1;
    if (mt + 1 < 32) {
#pragma unroll
      for (int i = 0; i < 2; ++i) {
        int idx = w * 2 + i;
        gload16(hp_sw + (size_t)(b * 32 + mt + 1) * 4096 + (idx * 64 + l) * 8,
                &Cs[cur ^ 1][idx * 512]);
      }
      if (t < 64) {
        Mv[cur ^ 1][t] = Mbuf[b * NN + (mt + 1) * 64 + t];
        Dv[cur ^ 1][t] = iDbuf[b * NN + (mt + 1) * 64 + t];
      }
    }
#pragma unroll
    for (int mf = 0; mf < 4; ++mf) {
      bf16x8 a0 = *(const bf16x8*)&Cs[cur][((lg) * 64 + mf * 16 + lr) * 8];
      bf16x8 a1 = *(const bf16x8*)&Cs[cur][((lg + 4) * 64 + mf * 16 + lr) * 8];
      f32x4 z;
      z[0] = 0.f; z[1] = 0.f; z[2] = 0.f; z[3] = 0.f;
      z = mfma16(a0, bq0, z);
      z = mfma16(a1, bq1, z);
      const float4 mv = *(const float4*)&Mv[cur][mf * 16 + lg * 4];
      const float4 dv = *(const float4*)&Dv[cur][mf * 16 + lg * 4];
      S += __expf(lrelu(z[0]) - mv.x) * dv.x;
      S += __expf(lrelu(z[1]) - mv.y) * dv.y;
      S += __expf(lrelu(z[2]) - mv.z) * dv.z;
      S += __expf(lrelu(z[3]) - mv.w) * dv.w;
    }
    __syncthreads();
  }
  S += __shfl_xor(S, 16);
  S += __shfl_xor(S, 32);
  if (l < 16) Sv[(w << 4) + l] = S;
  __syncthreads();
  // out write: 64 rows x 64 cols fp32
  const int row = t >> 2;
  const int c0 = (t & 3) * 16;
  const float sc = Sv[row];
  const size_t R = (size_t)b * NN + n0 + row;
#pragma unroll
  for (int hh = 0; hh < 2; ++hh) {
    const int kb = (t & 3) * 2 + hh;
    const u16* src = &Rs[(kb * 64 + row) * 8];
    float4 o0, o1;
    o0.x = bf2f(src[0]) * sc;
    o0.y = bf2f(src[1]) * sc;
    o0.z = bf2f(src[2]) * sc;
    o0.w = bf2f(src[3]) * sc;
    o1.x = bf2f(src[4]) * sc;
    o1.y = bf2f(src[5]) * sc;
    o1.z = bf2f(src[6]) * sc;
    o1.w = bf2f(src[7]) * sc;
    *(float4*)&out[R * NO + kb * 8] = o0;
    *(float4*)&out[R * NO + kb * 8 + 4] = o1;
  }
}

extern "C" void kernel_launch(void* const* d_in, const int* in_sizes, int n_in,
                              void* d_out, int out_size, void* d_ws, size_t ws_size,
                              hipStream_t stream) {
  const float* x = (const float*)d_in[0];
  // d_in[1] = adj (unused)
  const float* adj_gcn = (const float*)d_in[2];
  const float* gcn_w = (const float*)d_in[3];
  const float* gcn_b = (const float*)d_in[4];
  const float* gamma = (const float*)d_in[5];
  const float* beta = (const float*)d_in[6];
  const float* gat_w = (const float*)d_in[7];
  float* out = (float*)d_out;
  float* ws = (float*)d_ws;

  // workspace layout (float units):
  float* supp = ws;                        // 4,194,304 f (16MB), dead after k_tcast
  float* hbuf = ws;                        // reuses supp region (16MB)
  u16* suppT = (u16*)(ws + 4194304);       // 8MB
  u16* adjbf = (u16*)(ws + 6291456);       // 8MB
  u16* hp_sw = (u16*)(ws + 8388608);       // 4MB
  float* Mbuf = ws + 9437184;              // 32768
  float* iDbuf = ws + 9469952;             // 32768
  float* psum = ws + 9502720;              // 32768
  float* psq = ws + 9535488;               // 32768
  float* scale = ws + 9568256;             // 128
  float* shift = scale + 128;              // 128
  float* gWT = ws + 9568512;               // 8192

  k_support<<<dim3(NB * NN), dim3(128), 0, stream>>>(x, gcn_w, supp);
  k_tcast<<<dim3(512, 2), dim3(256), 0, stream>>>(supp, suppT);
  k_cast_adj<<<dim3(1024), dim3(256), 0, stream>>>(adj_gcn, adjbf);
  k_wt<<<dim3(1), dim3(256), 0, stream>>>(gat_w, gWT);
  k_gcn<<<dim3(32, 16), dim3(256), 0, stream>>>(adjbf, suppT, gcn_b, hbuf);
  k_bnstat1<<<dim3(256), dim3(256), 0, stream>>>(hbuf, psum, psq);
  k_bnstat2<<<dim3(1), dim3(1024), 0, stream>>>(psum, psq, gamma, beta, scale, shift);
  k_hp<<<dim3(512), dim3(256), 0, stream>>>(hbuf, scale, shift, gWT, hp_sw);
  k_attnA<<<dim3(NB * 32), dim3(256), 0, stream>>>(hp_sw, Mbuf, iDbuf);
  k_attnB<<<dim3(NB * 32), dim3(256), 0, stream>>>(hp_sw, Mbuf, iDbuf, out);
}

// Round 3
// 191.216 us; speedup vs baseline: 3.6291x; 1.2904x over previous
//
#include <hip/hip_runtime.h>
#include <math.h>

#define NB 16
#define NN 2048
#define NF 128
#define NH 128
#define NO 64

typedef short bf16x8 __attribute__((ext_vector_type(8)));
typedef float f32x4 __attribute__((ext_vector_type(4)));
typedef unsigned short u16;
typedef unsigned int u32;

__device__ __forceinline__ u16 f2bf(float f) {
  u32 u = __builtin_bit_cast(u32, f);
  return (u16)((u + 0x7fffu + ((u >> 16) & 1u)) >> 16);
}
__device__ __forceinline__ float bf2f(u16 h) {
  u32 u = ((u32)h) << 16;
  return __builtin_bit_cast(float, u);
}
__device__ __forceinline__ float lrelu(float x) { return x > 0.f ? x : 0.2f * x; }

__device__ __forceinline__ void gload16(const void* g, void* l) {
  __builtin_amdgcn_global_load_lds((const __attribute__((address_space(1))) void*)g,
                                   (__attribute__((address_space(3))) void*)l, 16, 0, 0);
}
__device__ __forceinline__ f32x4 mfma16(bf16x8 a, bf16x8 b, f32x4 c) {
  return __builtin_amdgcn_mfma_f32_16x16x32_bf16(a, b, c, 0, 0, 0);
}

// ---------------- K0: cast 4M fp32 -> bf16 (used for x and adj) --------------
__global__ __launch_bounds__(256) void k_cast(const float* __restrict__ a,
                                              u16* __restrict__ o) {
  const int i = blockIdx.x * 256 + threadIdx.x;
#pragma unroll
  for (int k = 0; k < 4; ++k) {
    int v4 = i + k * 262144;  // 1,048,576 float4s total
    float4 f = *(const float4*)&a[(size_t)v4 * 4];
    u32 r0 = (u32)f2bf(f.x) | ((u32)f2bf(f.y) << 16);
    u32 r1 = (u32)f2bf(f.z) | ((u32)f2bf(f.w) << 16);
    uint2 r;
    r.x = r0;
    r.y = r1;
    *(uint2*)&o[(size_t)v4 * 4] = r;
  }
}

// ---------------- K1: prep weights -------------------------------------------
// block 0: gWT[c][k] = gat_w[k][c] fp32
// blocks 1..8: Wsw bf16 in B-frag LDS image: slot s=[kblk 16][d 128] -> W[kb*8+j][d]
__global__ __launch_bounds__(256) void k_prep(const float* __restrict__ gcn_w,
                                              const float* __restrict__ gat_w,
                                              float* __restrict__ gWT,
                                              u16* __restrict__ Wsw) {
  const int t = threadIdx.x;
  if (blockIdx.x == 0) {
    const int c = t & 63, kq = t >> 6;
    for (int k = kq * 32; k < kq * 32 + 32; ++k) gWT[c * 128 + k] = gat_w[k * 64 + c];
  } else {
    const int s = (blockIdx.x - 1) * 256 + t;  // 2048 slots
    const int kb = s >> 7, d = s & 127;
    u16 tmp[8];
#pragma unroll
    for (int j = 0; j < 8; ++j) tmp[j] = f2bf(gcn_w[(kb * 8 + j) * 128 + d]);
    uint4 o;
    o.x = (u32)tmp[0] | ((u32)tmp[1] << 16);
    o.y = (u32)tmp[2] | ((u32)tmp[3] << 16);
    o.z = (u32)tmp[4] | ((u32)tmp[5] << 16);
    o.w = (u32)tmp[6] | ((u32)tmp[7] << 16);
    *(uint4*)&Wsw[(size_t)s * 8] = o;
  }
}

// ---------------- K2: support MFMA GEMM: suppT = (x @ W)^T bf16 --------------
// 128 rows per block, full K=128 staged once. 4 waves, wave-tile 32m x 128d.
__global__ __launch_bounds__(256) void k_support(const u16* __restrict__ xbf,
                                                 const u16* __restrict__ Wsw,
                                                 u16* __restrict__ suppT) {
  const int m0g = blockIdx.x * 128;
  const int t = threadIdx.x, w = t >> 6, l = t & 63;
  const int lg = l >> 4, lr = l & 15;
  __shared__ __align__(16) u16 sh[32768];  // 64KB: As[16384] | Bs[16384]; reused as os
  u16* As = sh;
  u16* Bs = sh + 16384;
#pragma unroll
  for (int i = 0; i < 8; ++i) {
    const int s = i * 256 + t;
    const int kb = s >> 7, row = s & 127;
    gload16(xbf + (size_t)(m0g + row) * 128 + kb * 8, &As[(size_t)s * 8]);
  }
#pragma unroll
  for (int i = 0; i < 8; ++i) {
    const int s = i * 256 + t;
    gload16(Wsw + (size_t)s * 8, &Bs[(size_t)s * 8]);
  }
  __syncthreads();
  f32x4 acc[2][8];
#pragma unroll
  for (int mf = 0; mf < 2; ++mf)
#pragma unroll
    for (int nf = 0; nf < 8; ++nf) {
      acc[mf][nf][0] = 0.f; acc[mf][nf][1] = 0.f;
      acc[mf][nf][2] = 0.f; acc[mf][nf][3] = 0.f;
    }
#pragma unroll
  for (int ks = 0; ks < 4; ++ks) {
    const int kb = ks * 4 + lg;
    const bf16x8 a0 = *(const bf16x8*)&As[((size_t)kb * 128 + w * 32 + lr) * 8];
    const bf16x8 a1 = *(const bf16x8*)&As[((size_t)kb * 128 + w * 32 + 16 + lr) * 8];
#pragma unroll
    for (int nf = 0; nf < 8; ++nf) {
      const bf16x8 b = *(const bf16x8*)&Bs[((size_t)kb * 128 + nf * 16 + lr) * 8];
      acc[0][nf] = mfma16(a0, b, acc[0][nf]);
      acc[1][nf] = mfma16(a1, b, acc[1][nf]);
    }
  }
  __syncthreads();
  // transpose through LDS: os[d][m], stride 136 u16
  u16* os = sh;
#pragma unroll
  for (int nf = 0; nf < 8; ++nf) {
    const int d = nf * 16 + lr;
#pragma unroll
    for (int mf = 0; mf < 2; ++mf) {
      const int mb = w * 32 + mf * 16 + lg * 4;
      u32 p0 = (u32)f2bf(acc[mf][nf][0]) | ((u32)f2bf(acc[mf][nf][1]) << 16);
      u32 p1 = (u32)f2bf(acc[mf][nf][2]) | ((u32)f2bf(acc[mf][nf][3]) << 16);
      *(u32*)&os[d * 136 + mb] = p0;
      *(u32*)&os[d * 136 + mb + 2] = p1;
    }
  }
  __syncthreads();
  const int b = m0g >> 11, mloc = m0g & 2047;
#pragma unroll
  for (int i = 0; i < 8; ++i) {
    const int s = i * 256 + t;  // 2048 16B slots
    const int d = s >> 4, j8 = s & 15;
    const uint4 v = *(const uint4*)&os[d * 136 + j8 * 8];
    *(uint4*)&suppT[((size_t)(b * 128 + d)) * 2048 + mloc + j8 * 8] = v;
  }
}

// ---------------- K5: GCN GEMM (bf16 MFMA): h = adj @ supp + bias ------------
__global__ __launch_bounds__(256) void k_gcn(const u16* __restrict__ adjbf,
                                             const u16* __restrict__ suppT,
                                             const float* __restrict__ bias,
                                             float* __restrict__ h) {
  const int n0 = blockIdx.x * 64;
  const int b = blockIdx.y;
  const int t = threadIdx.x;
  const int w = t >> 6, l = t & 63;
  const int wm = w >> 1, wn = w & 1;
  __shared__ __align__(16) u16 As[2][2048];  // [4 kblk][64 row][8]
  __shared__ __align__(16) u16 Bs[2][4096];  // [4 kblk][128 d][8]

  f32x4 acc[2][4];
#pragma unroll
  for (int mf = 0; mf < 2; ++mf)
#pragma unroll
    for (int nf = 0; nf < 4; ++nf) {
      acc[mf][nf][0] = 0.f; acc[mf][nf][1] = 0.f;
      acc[mf][nf][2] = 0.f; acc[mf][nf][3] = 0.f;
    }

#define GCN_STAGE(buf, k0)                                                      \
  {                                                                             \
    _Pragma("unroll") for (int i = 0; i < 3; ++i) {                             \
      int idx = w * 3 + i;                                                      \
      if (idx < 4) {                                                            \
        int slot = idx * 64 + l;                                                \
        int kb = slot >> 6, row = slot & 63;                                    \
        gload16(adjbf + (size_t)(n0 + row) * 2048 + (k0) + kb * 8,              \
                &As[buf][idx * 512]);                                           \
      } else {                                                                  \
        int slot = (idx - 4) * 64 + l;                                          \
        int kb = slot >> 7, d = slot & 127;                                     \
        gload16(suppT + (((size_t)(b * 128 + d)) << 11) + (k0) + kb * 8,        \
                &Bs[buf][(idx - 4) * 512]);                                     \
      }                                                                         \
    }                                                                           \
  }

  GCN_STAGE(0, 0);
  __syncthreads();
  const int lg = l >> 4, lr = l & 15;
  for (int ks = 0; ks < 64; ++ks) {
    const int cur = ks & 1;
    if (ks + 1 < 64) GCN_STAGE(cur ^ 1, (ks + 1) * 32);
    bf16x8 a0 = *(const bf16x8*)&As[cur][(lg * 64 + wm * 32 + 0 + lr) * 8];
    bf16x8 a1 = *(const bf16x8*)&As[cur][(lg * 64 + wm * 32 + 16 + lr) * 8];
    bf16x8 b0 = *(const bf16x8*)&Bs[cur][(lg * 128 + wn * 64 + 0 + lr) * 8];
    bf16x8 b1 = *(const bf16x8*)&Bs[cur][(lg * 128 + wn * 64 + 16 + lr) * 8];
    bf16x8 b2 = *(const bf16x8*)&Bs[cur][(lg * 128 + wn * 64 + 32 + lr) * 8];
    bf16x8 b3 = *(const bf16x8*)&Bs[cur][(lg * 128 + wn * 64 + 48 + lr) * 8];
    acc[0][0] = mfma16(a0, b0, acc[0][0]);
    acc[0][1] = mfma16(a0, b1, acc[0][1]);
    acc[0][2] = mfma16(a0, b2, acc[0][2]);
    acc[0][3] = mfma16(a0, b3, acc[0][3]);
    acc[1][0] = mfma16(a1, b0, acc[1][0]);
    acc[1][1] = mfma16(a1, b1, acc[1][1]);
    acc[1][2] = mfma16(a1, b2, acc[1][2]);
    acc[1][3] = mfma16(a1, b3, acc[1][3]);
    __syncthreads();
  }
#undef GCN_STAGE
#pragma unroll
  for (int nf = 0; nf < 4; ++nf) {
    const int d = wn * 64 + nf * 16 + lr;
    const float bv = bias[d];
#pragma unroll
    for (int mf = 0; mf < 2; ++mf) {
#pragma unroll
      for (int r = 0; r < 4; ++r) {
        const int row = n0 + wm * 32 + mf * 16 + lg * 4 + r;
        h[((size_t)(b * NN + row)) * NH + d] = acc[mf][nf][r] + bv;
      }
    }
  }
}

// ---------------- BN stats ---------------------------------------------------
__global__ __launch_bounds__(256) void k_bnstat1(const float* __restrict__ h,
                                                 float* __restrict__ psum,
                                                 float* __restrict__ psq) {
  const int blk = blockIdx.x;
  const int t = threadIdx.x;
  const int d = t & 127;
  const int rh = t >> 7;
  float s = 0.f, q = 0.f;
  for (int r = rh; r < 128; r += 2) {
    const float v = h[((size_t)blk * 128 + r) * NH + d];
    s += v;
    q = fmaf(v, v, q);
  }
  __shared__ float ls[2][128], lq[2][128];
  ls[rh][d] = s;
  lq[rh][d] = q;
  __syncthreads();
  if (t < 128) {
    psum[blk * 128 + t] = ls[0][t] + ls[1][t];
    psq[blk * 128 + t] = lq[0][t] + lq[1][t];
  }
}

__global__ __launch_bounds__(1024) void k_bnstat2(const float* __restrict__ psum,
                                                  const float* __restrict__ psq,
                                                  const float* __restrict__ gamma,
                                                  const float* __restrict__ beta,
                                                  float* __restrict__ scale,
                                                  float* __restrict__ shift) {
  const int t = threadIdx.x;
  const int d = t & 127;
  const int g = t >> 7;
  float s = 0.f, q = 0.f;
  for (int i = g; i < 256; i += 8) {
    s += psum[i * 128 + d];
    q += psq[i * 128 + d];
  }
  __shared__ float ls[8][128], lq[8][128];
  ls[g][d] = s;
  lq[g][d] = q;
  __syncthreads();
  if (t < 128) {
    s = 0.f;
    q = 0.f;
#pragma unroll
    for (int i = 0; i < 8; ++i) {
      s += ls[i][t];
      q += lq[i][t];
    }
    const float inv = 1.f / (float)(NB * NN);
    const float mean = s * inv;
    const float var = q * inv - mean * mean;
    const float sc = gamma[t] * rsqrtf(var + 1e-5f);
    scale[t] = sc;
    shift[t] = beta[t] - mean * sc;
  }
}

// ---------------- K6: hp = relu(bn(h)) @ gat_W, written pre-swizzled bf16 ----
__global__ __launch_bounds__(256) void k_hp(const float* __restrict__ h,
                                            const float* __restrict__ scale,
                                            const float* __restrict__ shift,
                                            const float* __restrict__ gWT,
                                            u16* __restrict__ hp_sw) {
  const int row0 = blockIdx.x * 64;
  __shared__ float hs[64][132];
  __shared__ __align__(16) u16 hos[64][72];
  const int t = threadIdx.x;
#pragma unroll
  for (int k = 0; k < 8; ++k) {
    int s = t + k * 256;
    int row = s >> 5, c4 = (s & 31) * 4;
    float4 v = *(const float4*)&h[(size_t)(row0 + row) * NH + c4];
    float4 sc = *(const float4*)&scale[c4];
    float4 sh = *(const float4*)&shift[c4];
    hs[row][c4 + 0] = fmaxf(fmaf(v.x, sc.x, sh.x), 0.f);
    hs[row][c4 + 1] = fmaxf(fmaf(v.y, sc.y, sh.y), 0.f);
    hs[row][c4 + 2] = fmaxf(fmaf(v.z, sc.z, sh.z), 0.f);
    hs[row][c4 + 3] = fmaxf(fmaf(v.w, sc.w, sh.w), 0.f);
  }
  __syncthreads();
  const int c = t & 63, q = t >> 6;
  float acc[16];
#pragma unroll
  for (int r = 0; r < 16; ++r) acc[r] = 0.f;
  for (int c4 = 0; c4 < 32; ++c4) {
    const float4 wv = *(const float4*)&gWT[c * 128 + c4 * 4];
#pragma unroll
    for (int r = 0; r < 16; ++r) {
      const float4 hv = *(const float4*)&hs[q * 16 + r][c4 * 4];
      acc[r] = fmaf(hv.x, wv.x, fmaf(hv.y, wv.y, fmaf(hv.z, wv.z, fmaf(hv.w, wv.w, acc[r]))));
    }
  }
#pragma unroll
  for (int r = 0; r < 16; ++r) hos[q * 16 + r][c] = f2bf(acc[r]);
  __syncthreads();
  const size_t tbase = (size_t)blockIdx.x * 4096;
#pragma unroll
  for (int k = 0; k < 2; ++k) {
    int s = t + k * 256;
    int kb = s >> 6, r6 = s & 63;
    uint2 lo = *(const uint2*)&hos[r6][kb * 8];
    uint2 hi = *(const uint2*)&hos[r6][kb * 8 + 4];
    uint4 o;
    o.x = lo.x; o.y = lo.y; o.z = hi.x; o.w = hi.y;
    *(uint4*)&hp_sw[tbase + kb * 512 + r6 * 8] = o;
  }
}

// ---------------- K7: attn pass A ------------------------------------------
__global__ __launch_bounds__(256) void k_attnA(const u16* __restrict__ hp_sw,
                                               float* __restrict__ Mbuf,
                                               float* __restrict__ iDbuf) {
  const int b = blockIdx.x >> 5;
  const int n0 = (blockIdx.x & 31) << 6;
  const int t = threadIdx.x, w = t >> 6, l = t & 63;
  const int lg = l >> 4, lr = l & 15;
  __shared__ __align__(16) u16 Rs[4096];
  __shared__ __align__(16) u16 Cs[2][4096];

  const int tileR = b * 32 + (n0 >> 6);
#pragma unroll
  for (int i = 0; i < 2; ++i) {
    int idx = w * 2 + i;
    gload16(hp_sw + (size_t)tileR * 4096 + (idx * 64 + l) * 8, &Rs[idx * 512]);
  }
#pragma unroll
  for (int i = 0; i < 2; ++i) {
    int idx = w * 2 + i;
    gload16(hp_sw + (size_t)(b * 32) * 4096 + (idx * 64 + l) * 8, &Cs[0][idx * 512]);
  }
  __syncthreads();
  const bf16x8 bq0 = *(const bf16x8*)&Rs[((lg) * 64 + (w << 4) + lr) * 8];
  const bf16x8 bq1 = *(const bf16x8*)&Rs[((lg + 4) * 64 + (w << 4) + lr) * 8];
  float M = -3.4e38f, S = 0.f;
  for (int mt = 0; mt < 32; ++mt) {
    const int cur = mt & 1;
    if (mt + 1 < 32) {
#pragma unroll
      for (int i = 0; i < 2; ++i) {
        int idx = w * 2 + i;
        gload16(hp_sw + (size_t)(b * 32 + mt + 1) * 4096 + (idx * 64 + l) * 8,
                &Cs[cur ^ 1][idx * 512]);
      }
    }
    f32x4 e[4];
#pragma unroll
    for (int mf = 0; mf < 4; ++mf) {
      bf16x8 a0 = *(const bf16x8*)&Cs[cur][((lg) * 64 + mf * 16 + lr) * 8];
      bf16x8 a1 = *(const bf16x8*)&Cs[cur][((lg + 4) * 64 + mf * 16 + lr) * 8];
      f32x4 z;
      z[0] = 0.f; z[1] = 0.f; z[2] = 0.f; z[3] = 0.f;
      z = mfma16(a0, bq0, z);
      z = mfma16(a1, bq1, z);
      e[mf] = z;
    }
    float vv[4][4];
    float tmax = -3.4e38f;
#pragma unroll
    for (int mf = 0; mf < 4; ++mf)
#pragma unroll
      for (int r = 0; r < 4; ++r) {
        float v = lrelu(e[mf][r]);
        vv[mf][r] = v;
        tmax = fmaxf(tmax, v);
      }
    tmax = fmaxf(tmax, __shfl_xor(tmax, 16));
    tmax = fmaxf(tmax, __shfl_xor(tmax, 32));
    const float newM = fmaxf(M, tmax);
    float p = 0.f;
#pragma unroll
    for (int mf = 0; mf < 4; ++mf)
#pragma unroll
      for (int r = 0; r < 4; ++r) p += __expf(vv[mf][r] - newM);
    p += __shfl_xor(p, 16);
    p += __shfl_xor(p, 32);
    S = S * __expf(M - newM) + p;
    M = newM;
    __syncthreads();
  }
  if (l < 16) {
    Mbuf[b * NN + n0 + (w << 4) + l] = M;
    iDbuf[b * NN + n0 + (w << 4) + l] = 1.f / S;
  }
}

// ---------------- K8: attn pass B ------------------------------------------
__global__ __launch_bounds__(256) void k_attnB(const u16* __restrict__ hp_sw,
                                               const float* __restrict__ Mbuf,
                                               const float* __restrict__ iDbuf,
                                               float* __restrict__ out) {
  const int b = blockIdx.x >> 5;
  const int n0 = (blockIdx.x & 31) << 6;
  const int t = threadIdx.x, w = t >> 6, l = t & 63;
  const int lg = l >> 4, lr = l & 15;
  __shared__ __align__(16) u16 Rs[4096];
  __shared__ __align__(16) u16 Cs[2][4096];
  __shared__ __align__(16) float Mv[2][64], Dv[2][64];
  __shared__ float Sv[64];

  const int tileR = b * 32 + (n0 >> 6);
#pragma unroll
  for (int i = 0; i < 2; ++i) {
    int idx = w * 2 + i;
    gload16(hp_sw + (size_t)tileR * 4096 + (idx * 64 + l) * 8, &Rs[idx * 512]);
  }
#pragma unroll
  for (int i = 0; i < 2; ++i) {
    int idx = w * 2 + i;
    gload16(hp_sw + (size_t)(b * 32) * 4096 + (idx * 64 + l) * 8, &Cs[0][idx * 512]);
  }
  if (t < 64) {
    Mv[0][t] = Mbuf[b * NN + t];
    Dv[0][t] = iDbuf[b * NN + t];
  }
  __syncthreads();
  const bf16x8 bq0 = *(const bf16x8*)&Rs[((lg) * 64 + (w << 4) + lr) * 8];
  const bf16x8 bq1 = *(const bf16x8*)&Rs[((lg + 4) * 64 + (w << 4) + lr) * 8];
  float S = 0.f;
  for (int mt = 0; mt < 32; ++mt) {
    const int cur = mt & 1;
    if (mt + 1 < 32) {
#pragma unroll
      for (int i = 0; i < 2; ++i) {
        int idx = w * 2 + i;
        gload16(hp_sw + (size_t)(b * 32 + mt + 1) * 4096 + (idx * 64 + l) * 8,
                &Cs[cur ^ 1][idx * 512]);
      }
      if (t < 64) {
        Mv[cur ^ 1][t] = Mbuf[b * NN + (mt + 1) * 64 + t];
        Dv[cur ^ 1][t] = iDbuf[b * NN + (mt + 1) * 64 + t];
      }
    }
#pragma unroll
    for (int mf = 0; mf < 4; ++mf) {
      bf16x8 a0 = *(const bf16x8*)&Cs[cur][((lg) * 64 + mf * 16 + lr) * 8];
      bf16x8 a1 = *(const bf16x8*)&Cs[cur][((lg + 4) * 64 + mf * 16 + lr) * 8];
      f32x4 z;
      z[0] = 0.f; z[1] = 0.f; z[2] = 0.f; z[3] = 0.f;
      z = mfma16(a0, bq0, z);
      z = mfma16(a1, bq1, z);
      const float4 mv = *(const float4*)&Mv[cur][mf * 16 + lg * 4];
      const float4 dv = *(const float4*)&Dv[cur][mf * 16 + lg * 4];
      S += __expf(lrelu(z[0]) - mv.x) * dv.x;
      S += __expf(lrelu(z[1]) - mv.y) * dv.y;
      S += __expf(lrelu(z[2]) - mv.z) * dv.z;
      S += __expf(lrelu(z[3]) - mv.w) * dv.w;
    }
    __syncthreads();
  }
  S += __shfl_xor(S, 16);
  S += __shfl_xor(S, 32);
  if (l < 16) Sv[(w << 4) + l] = S;
  __syncthreads();
  const int row = t >> 2;
  const float sc = Sv[row];
  const size_t R = (size_t)b * NN + n0 + row;
#pragma unroll
  for (int hh = 0; hh < 2; ++hh) {
    const int kb = (t & 3) * 2 + hh;
    const u16* src = &Rs[(kb * 64 + row) * 8];
    float4 o0, o1;
    o0.x = bf2f(src[0]) * sc;
    o0.y = bf2f(src[1]) * sc;
    o0.z = bf2f(src[2]) * sc;
    o0.w = bf2f(src[3]) * sc;
    o1.x = bf2f(src[4]) * sc;
    o1.y = bf2f(src[5]) * sc;
    o1.z = bf2f(src[6]) * sc;
    o1.w = bf2f(src[7]) * sc;
    *(float4*)&out[R * NO + kb * 8] = o0;
    *(float4*)&out[R * NO + kb * 8 + 4] = o1;
  }
}

extern "C" void kernel_launch(void* const* d_in, const int* in_sizes, int n_in,
                              void* d_out, int out_size, void* d_ws, size_t ws_size,
                              hipStream_t stream) {
  const float* x = (const float*)d_in[0];
  // d_in[1] = adj (unused)
  const float* adj_gcn = (const float*)d_in[2];
  const float* gcn_w = (const float*)d_in[3];
  const float* gcn_b = (const float*)d_in[4];
  const float* gamma = (const float*)d_in[5];
  const float* beta = (const float*)d_in[6];
  const float* gat_w = (const float*)d_in[7];
  float* out = (float*)d_out;
  float* ws = (float*)d_ws;

  // workspace layout (float units), peak ~9.13M floats (36.5MB):
  u16* suppT = (u16*)ws;                   // [0, 2M) floats: 4M u16
  u16* adjbf = (u16*)(ws + 2097152);       // [2M, 4M)
  float* hbuf = ws + 4194304;              // [4M, 8M): 16MB fp32
  u16* xbf = (u16*)(ws + 4194304);         // [4M, 6M) — dead before hbuf written
  u16* hp_sw = (u16*)(ws + 8388608);       // [8M, 9M)
  float* Mbuf = ws + 9437184;              // 32768
  float* iDbuf = Mbuf + 32768;             // 32768
  float* psum = iDbuf + 32768;             // 32768
  float* psq = psum + 32768;               // 32768
  float* scale = psq + 32768;              // 128
  float* shift = scale + 128;              // 128
  float* gWT = shift + 128;                // 8192
  u16* Wsw = (u16*)(gWT + 8192);           // 16384 u16

  k_cast<<<dim3(1024), dim3(256), 0, stream>>>(x, xbf);
  k_cast<<<dim3(1024), dim3(256), 0, stream>>>(adj_gcn, adjbf);
  k_prep<<<dim3(9), dim3(256), 0, stream>>>(gcn_w, gat_w, gWT, Wsw);
  k_support<<<dim3(256), dim3(256), 0, stream>>>(xbf, Wsw, suppT);
  k_gcn<<<dim3(32, 16), dim3(256), 0, stream>>>(adjbf, suppT, gcn_b, hbuf);
  k_bnstat1<<<dim3(256), dim3(256), 0, stream>>>(hbuf, psum, psq);
  k_bnstat2<<<dim3(1), dim3(1024), 0, stream>>>(psum, psq, gamma, beta, scale, shift);
  k_hp<<<dim3(512), dim3(256), 0, stream>>>(hbuf, scale, shift, gWT, hp_sw);
  k_attnA<<<dim3(NB * 32), dim3(256), 0, stream>>>(hp_sw, Mbuf, iDbuf);
  k_attnB<<<dim3(NB * 32), dim3(256), 0, stream>>>(hp_sw, Mbuf, iDbuf, out);
}

// Round 5
// 137.391 us; speedup vs baseline: 5.0509x; 1.3918x over previous
//
#include <hip/hip_runtime.h>
#include <math.h>

#define NB 16
#define NN 2048
#define NF 128
#define NH 128
#define NO 64

typedef short bf16x8 __attribute__((ext_vector_type(8)));
typedef float f32x4 __attribute__((ext_vector_type(4)));
typedef unsigned short u16;
typedef unsigned int u32;

__device__ __forceinline__ u16 f2bf(float f) {
  u32 u = __builtin_bit_cast(u32, f);
  return (u16)((u + 0x7fffu + ((u >> 16) & 1u)) >> 16);
}
__device__ __forceinline__ float bf2f(u16 h) {
  u32 u = ((u32)h) << 16;
  return __builtin_bit_cast(float, u);
}
__device__ __forceinline__ float lrelu(float x) { return x > 0.f ? x : 0.2f * x; }

__device__ __forceinline__ void gload16(const void* g, void* l) {
  __builtin_amdgcn_global_load_lds((const __attribute__((address_space(1))) void*)g,
                                   (__attribute__((address_space(3))) void*)l, 16, 0, 0);
}
__device__ __forceinline__ f32x4 mfma16(bf16x8 a, bf16x8 b, f32x4 c) {
  return __builtin_amdgcn_mfma_f32_16x16x32_bf16(a, b, c, 0, 0, 0);
}

// ---------------- K_prep: all input preprocessing in one kernel --------------
// bid 0      : gWT[c][k] = gat_w[k][c] (fp32)
// bid 1..8   : Wsw  = gcn_w bf16 in [kblk 16][d 128][8] image
// bid 9..264 : x_sw = x bf16 in [rowblk 256][kblk 16][row 128][8] image
// bid 265..  : adj_sw = adj bf16 in [ntile 32][ktile 32][kblk 8][row 64][8] image
// NOTE: ts row stride 136 u16 (272B, 16B-aligned) — x path needs 128 cols/row.
__global__ __launch_bounds__(256) void k_prep(const float* __restrict__ x,
                                              const float* __restrict__ adj,
                                              const float* __restrict__ gcn_w,
                                              const float* __restrict__ gat_w,
                                              u16* __restrict__ x_sw,
                                              u16* __restrict__ adj_sw,
                                              float* __restrict__ gWT,
                                              u16* __restrict__ Wsw) {
  __shared__ u16 ts[128 * 136];
  const int t = threadIdx.x;
  const int bid = blockIdx.x;
  if (bid == 0) {
    const int c = t & 63, kq = t >> 6;
    for (int k = kq * 32; k < kq * 32 + 32; ++k) gWT[c * 128 + k] = gat_w[k * 64 + c];
  } else if (bid < 9) {
    const int s = (bid - 1) * 256 + t;  // [kb 16][d 128]
    const int kb = s >> 7, d = s & 127;
    u16 tmp[8];
#pragma unroll
    for (int j = 0; j < 8; ++j) tmp[j] = f2bf(gcn_w[(kb * 8 + j) * 128 + d]);
    uint4 o;
    o.x = (u32)tmp[0] | ((u32)tmp[1] << 16);
    o.y = (u32)tmp[2] | ((u32)tmp[3] << 16);
    o.z = (u32)tmp[4] | ((u32)tmp[5] << 16);
    o.w = (u32)tmp[6] | ((u32)tmp[7] << 16);
    *(uint4*)&Wsw[(size_t)s * 8] = o;
  } else if (bid < 265) {
    const int blk = bid - 9;  // 128 rows of x
    const size_t r0 = (size_t)blk * 128;
#pragma unroll
    for (int k = 0; k < 16; ++k) {
      const int s = t + k * 256;  // 4096 float4 slots
      const int row = s >> 5, c4 = (s & 31) * 4;
      const float4 f = *(const float4*)&x[(r0 + row) * 128 + c4];
      uint2 pk;
      pk.x = (u32)f2bf(f.x) | ((u32)f2bf(f.y) << 16);
      pk.y = (u32)f2bf(f.z) | ((u32)f2bf(f.w) << 16);
      *(uint2*)&ts[row * 136 + c4] = pk;
    }
    __syncthreads();
#pragma unroll
    for (int k = 0; k < 8; ++k) {
      const int s = t + k * 256;  // 2048 16B slots: [kb 16][row 128]
      const int kb = s >> 7, row = s & 127;
      const uint4 v = *(const uint4*)&ts[row * 136 + kb * 8];
      *(uint4*)&x_sw[(size_t)blk * 16384 + (size_t)s * 8] = v;
    }
  } else {
    const int tile = bid - 265;  // 64x64 tile of adj: [nt 32][kt 32]
    const int n0 = (tile >> 5) * 64, m0 = (tile & 31) * 64;
#pragma unroll
    for (int k = 0; k < 4; ++k) {
      const int s = t + k * 256;  // 1024 float4 slots
      const int row = s >> 4, c4 = (s & 15) * 4;
      const float4 f = *(const float4*)&adj[(size_t)(n0 + row) * 2048 + m0 + c4];
      uint2 pk;
      pk.x = (u32)f2bf(f.x) | ((u32)f2bf(f.y) << 16);
      pk.y = (u32)f2bf(f.z) | ((u32)f2bf(f.w) << 16);
      *(uint2*)&ts[row * 136 + c4] = pk;
    }
    __syncthreads();
#pragma unroll
    for (int k = 0; k < 2; ++k) {
      const int s = t + k * 256;  // 512 16B slots: [kb 8][row 64]
      const int kb = s >> 6, row = s & 63;
      const uint4 v = *(const uint4*)&ts[row * 136 + kb * 8];
      *(uint4*)&adj_sw[(size_t)tile * 4096 + (size_t)s * 8] = v;
    }
  }
}

// ---------------- K_support: suppT_sw = (x @ W)^T, pre-swizzled bf16 ---------
// 128 rows/block, full K=128 staged once (linear, coalesced). 4 waves.
// Output image: [(b*32 + ktile)][kblk 8][d 128][8]
__global__ __launch_bounds__(256) void k_support(const u16* __restrict__ x_sw,
                                                 const u16* __restrict__ Wsw,
                                                 u16* __restrict__ suppT_sw) {
  const int m0g = blockIdx.x * 128;
  const int t = threadIdx.x, w = t >> 6, l = t & 63;
  const int lg = l >> 4, lr = l & 15;
  __shared__ __align__(16) u16 sh[32768];  // 64KB stage; reused as os (34.8KB)
  u16* As = sh;
  u16* Bs = sh + 16384;
#pragma unroll
  for (int i = 0; i < 8; ++i) {
    const int s0 = i * 256 + w * 64;
    gload16(x_sw + (size_t)blockIdx.x * 16384 + (size_t)(s0 + l) * 8, &As[(size_t)s0 * 8]);
  }
#pragma unroll
  for (int i = 0; i < 8; ++i) {
    const int s0 = i * 256 + w * 64;
    gload16(Wsw + (size_t)(s0 + l) * 8, &Bs[(size_t)s0 * 8]);
  }
  __syncthreads();
  f32x4 acc[2][8];
#pragma unroll
  for (int mf = 0; mf < 2; ++mf)
#pragma unroll
    for (int nf = 0; nf < 8; ++nf) {
      acc[mf][nf][0] = 0.f; acc[mf][nf][1] = 0.f;
      acc[mf][nf][2] = 0.f; acc[mf][nf][3] = 0.f;
    }
#pragma unroll
  for (int ks = 0; ks < 4; ++ks) {
    const int kb = ks * 4 + lg;
    const bf16x8 a0 = *(const bf16x8*)&As[((size_t)kb * 128 + w * 32 + lr) * 8];
    const bf16x8 a1 = *(const bf16x8*)&As[((size_t)kb * 128 + w * 32 + 16 + lr) * 8];
#pragma unroll
    for (int nf = 0; nf < 8; ++nf) {
      const bf16x8 b = *(const bf16x8*)&Bs[((size_t)kb * 128 + nf * 16 + lr) * 8];
      acc[0][nf] = mfma16(a0, b, acc[0][nf]);
      acc[1][nf] = mfma16(a1, b, acc[1][nf]);
    }
  }
  __syncthreads();
  // transpose through LDS: os[d][m_local], stride 136 u16 (16B-aligned rows)
  u16* os = sh;
#pragma unroll
  for (int nf = 0; nf < 8; ++nf) {
    const int d = nf * 16 + lr;
#pragma unroll
    for (int mf = 0; mf < 2; ++mf) {
      const int mb = w * 32 + mf * 16 + lg * 4;
      const u32 p0 = (u32)f2bf(acc[mf][nf][0]) | ((u32)f2bf(acc[mf][nf][1]) << 16);
      const u32 p1 = (u32)f2bf(acc[mf][nf][2]) | ((u32)f2bf(acc[mf][nf][3]) << 16);
      *(u32*)&os[d * 136 + mb] = p0;
      *(u32*)&os[d * 136 + mb + 2] = p1;
    }
  }
  __syncthreads();
  const int b = m0g >> 11, mt0 = (m0g & 2047) >> 6;  // covers ktiles mt0, mt0+1
#pragma unroll
  for (int i = 0; i < 8; ++i) {
    const int s = i * 256 + t;  // 2048 16B slots: [kt 2][kb 8][d 128]
    const int kt = s >> 10, kb = (s >> 7) & 7, d = s & 127;
    const uint4 v = *(const uint4*)&os[d * 136 + kt * 64 + kb * 8];
    *(uint4*)&suppT_sw[((size_t)((b * 32 + mt0 + kt) * 8 + kb)) * 1024 + (size_t)d * 8] = v;
  }
}

// ---------------- K_gcn: h = adj @ supp + bias (+ fused BN partials) ---------
// 64x128 tile, BK=64, double-buffered linear staging. 4 waves, wave 32x64.
__global__ __launch_bounds__(256) void k_gcn(const u16* __restrict__ adj_sw,
                                             const u16* __restrict__ suppT_sw,
                                             const float* __restrict__ bias,
                                             float* __restrict__ h,
                                             float* __restrict__ psum,
                                             float* __restrict__ psq) {
  const int nt = blockIdx.x;
  const int b = blockIdx.y;
  const int n0 = nt * 64;
  const int t = threadIdx.x;
  const int w = t >> 6, l = t & 63;
  const int wm = w >> 1, wn = w & 1;
  const int lg = l >> 4, lr = l & 15;
  __shared__ __align__(16) u16 As[2][4096];  // [8 kblk][64 row][8]
  __shared__ __align__(16) u16 Bs[2][8192];  // [8 kblk][128 d][8]
  __shared__ float redS[2][128], redQ[2][128];

  f32x4 acc[2][4];
#pragma unroll
  for (int mf = 0; mf < 2; ++mf)
#pragma unroll
    for (int nf = 0; nf < 4; ++nf) {
      acc[mf][nf][0] = 0.f; acc[mf][nf][1] = 0.f;
      acc[mf][nf][2] = 0.f; acc[mf][nf][3] = 0.f;
    }

#define GCN_STAGE(buf, kt)                                                       \
  {                                                                              \
    _Pragma("unroll") for (int i = 0; i < 2; ++i) {                              \
      const int s0 = i * 256 + w * 64;                                           \
      gload16(adj_sw + ((size_t)(nt * 32 + (kt))) * 4096 + (size_t)(s0 + l) * 8, \
              &As[buf][s0 * 8]);                                                 \
    }                                                                            \
    _Pragma("unroll") for (int i = 0; i < 4; ++i) {                              \
      const int s0 = i * 256 + w * 64;                                           \
      gload16(suppT_sw + ((size_t)(b * 32 + (kt))) * 8192 + (size_t)(s0 + l) * 8,\
              &Bs[buf][s0 * 8]);                                                 \
    }                                                                            \
  }

  GCN_STAGE(0, 0);
  __syncthreads();
  for (int kt = 0; kt < 32; ++kt) {
    const int cur = kt & 1;
    if (kt + 1 < 32) GCN_STAGE(cur ^ 1, kt + 1);
#pragma unroll
    for (int kb = 0; kb < 2; ++kb) {
      const int ko = kb * 4 + lg;
      const bf16x8 a0 = *(const bf16x8*)&As[cur][(ko * 64 + wm * 32 + lr) * 8];
      const bf16x8 a1 = *(const bf16x8*)&As[cur][(ko * 64 + wm * 32 + 16 + lr) * 8];
      const bf16x8 b0 = *(const bf16x8*)&Bs[cur][(ko * 128 + wn * 64 + lr) * 8];
      const bf16x8 b1 = *(const bf16x8*)&Bs[cur][(ko * 128 + wn * 64 + 16 + lr) * 8];
      const bf16x8 b2 = *(const bf16x8*)&Bs[cur][(ko * 128 + wn * 64 + 32 + lr) * 8];
      const bf16x8 b3 = *(const bf16x8*)&Bs[cur][(ko * 128 + wn * 64 + 48 + lr) * 8];
      acc[0][0] = mfma16(a0, b0, acc[0][0]);
      acc[0][1] = mfma16(a0, b1, acc[0][1]);
      acc[0][2] = mfma16(a0, b2, acc[0][2]);
      acc[0][3] = mfma16(a0, b3, acc[0][3]);
      acc[1][0] = mfma16(a1, b0, acc[1][0]);
      acc[1][1] = mfma16(a1, b1, acc[1][1]);
      acc[1][2] = mfma16(a1, b2, acc[1][2]);
      acc[1][3] = mfma16(a1, b3, acc[1][3]);
    }
    __syncthreads();
  }
#undef GCN_STAGE
  // epilogue: add bias, store h, reduce BN partials
#pragma unroll
  for (int nf = 0; nf < 4; ++nf) {
    const int d = wn * 64 + nf * 16 + lr;
    const float bv = bias[d];
    float s = 0.f, q = 0.f;
#pragma unroll
    for (int mf = 0; mf < 2; ++mf) {
#pragma unroll
      for (int r = 0; r < 4; ++r) {
        const float v = acc[mf][nf][r] + bv;
        const int row = n0 + wm * 32 + mf * 16 + lg * 4 + r;
        h[((size_t)(b * NN + row)) * NH + d] = v;
        s += v;
        q = fmaf(v, v, q);
      }
    }
    s += __shfl_xor(s, 16);
    s += __shfl_xor(s, 32);
    q += __shfl_xor(q, 16);
    q += __shfl_xor(q, 32);
    if (lg == 0) {
      redS[wm][d] = s;
      redQ[wm][d] = q;
    }
  }
  __syncthreads();
  if (t < 128) {
    const int blk = b * 32 + nt;
    psum[blk * 128 + t] = redS[0][t] + redS[1][t];
    psq[blk * 128 + t] = redQ[0][t] + redQ[1][t];
  }
}

// ---------------- BN finalize (512 partials) ---------------------------------
__global__ __launch_bounds__(1024) void k_bnstat2(const float* __restrict__ psum,
                                                  const float* __restrict__ psq,
                                                  const float* __restrict__ gamma,
                                                  const float* __restrict__ beta,
                                                  float* __restrict__ scale,
                                                  float* __restrict__ shift) {
  const int t = threadIdx.x;
  const int d = t & 127;
  const int g = t >> 7;
  float s = 0.f, q = 0.f;
  for (int i = g; i < 512; i += 8) {
    s += psum[i * 128 + d];
    q += psq[i * 128 + d];
  }
  __shared__ float ls[8][128], lq[8][128];
  ls[g][d] = s;
  lq[g][d] = q;
  __syncthreads();
  if (t < 128) {
    s = 0.f;
    q = 0.f;
#pragma unroll
    for (int i = 0; i < 8; ++i) {
      s += ls[i][t];
      q += lq[i][t];
    }
    const float inv = 1.f / (float)(NB * NN);
    const float mean = s * inv;
    const float var = q * inv - mean * mean;
    const float sc = gamma[t] * rsqrtf(var + 1e-5f);
    scale[t] = sc;
    shift[t] = beta[t] - mean * sc;
  }
}

// ---------------- K_hp: hp = relu(bn(h)) @ gat_W, pre-swizzled bf16 ----------
__global__ __launch_bounds__(256) void k_hp(const float* __restrict__ h,
                                            const float* __restrict__ scale,
                                            const float* __restrict__ shift,
                                            const float* __restrict__ gWT,
                                            u16* __restrict__ hp_sw) {
  const int row0 = blockIdx.x * 64;
  __shared__ float hs[64][132];
  __shared__ __align__(16) u16 hos[64][72];
  const int t = threadIdx.x;
#pragma unroll
  for (int k = 0; k < 8; ++k) {
    const int s = t + k * 256;
    const int row = s >> 5, c4 = (s & 31) * 4;
    const float4 v = *(const float4*)&h[(size_t)(row0 + row) * NH + c4];
    const float4 sc = *(const float4*)&scale[c4];
    const float4 sh = *(const float4*)&shift[c4];
    hs[row][c4 + 0] = fmaxf(fmaf(v.x, sc.x, sh.x), 0.f);
    hs[row][c4 + 1] = fmaxf(fmaf(v.y, sc.y, sh.y), 0.f);
    hs[row][c4 + 2] = fmaxf(fmaf(v.z, sc.z, sh.z), 0.f);
    hs[row][c4 + 3] = fmaxf(fmaf(v.w, sc.w, sh.w), 0.f);
  }
  __syncthreads();
  const int c = t & 63, q = t >> 6;
  float acc[16];
#pragma unroll
  for (int r = 0; r < 16; ++r) acc[r] = 0.f;
  for (int c4 = 0; c4 < 32; ++c4) {
    const float4 wv = *(const float4*)&gWT[c * 128 + c4 * 4];
#pragma unroll
    for (int r = 0; r < 16; ++r) {
      const float4 hv = *(const float4*)&hs[q * 16 + r][c4 * 4];
      acc[r] = fmaf(hv.x, wv.x, fmaf(hv.y, wv.y, fmaf(hv.z, wv.z, fmaf(hv.w, wv.w, acc[r]))));
    }
  }
#pragma unroll
  for (int r = 0; r < 16; ++r) hos[q * 16 + r][c] = f2bf(acc[r]);
  __syncthreads();
  const size_t tbase = (size_t)blockIdx.x * 4096;
#pragma unroll
  for (int k = 0; k < 2; ++k) {
    const int s = t + k * 256;
    const int kb = s >> 6, r6 = s & 63;
    const uint2 lo = *(const uint2*)&hos[r6][kb * 8];
    const uint2 hi = *(const uint2*)&hos[r6][kb * 8 + 4];
    uint4 o;
    o.x = lo.x; o.y = lo.y; o.z = hi.x; o.w = hi.y;
    *(uint4*)&hp_sw[tbase + kb * 512 + r6 * 8] = o;
  }
}

// ---------------- K_attnA: D[n] = sum_m exp(lrelu(e[n,m]) - 30) --------------
// constant shift cancels exactly in attention = exp(e-30)/D; overflow guard.
__global__ __launch_bounds__(256) void k_attnA(const u16* __restrict__ hp_sw,
                                               float* __restrict__ iDbuf) {
  const int b = blockIdx.x >> 5;
  const int n0 = (blockIdx.x & 31) << 6;
  const int t = threadIdx.x, w = t >> 6, l = t & 63;
  const int lg = l >> 4, lr = l & 15;
  __shared__ __align__(16) u16 Rs[4096];
  __shared__ __align__(16) u16 Cs[2][8192];  // 2 x (two 64-row tiles)
  const int tileR = b * 32 + (n0 >> 6);
#pragma unroll
  for (int i = 0; i < 2; ++i) {
    const int idx = w * 2 + i;
    gload16(hp_sw + (size_t)tileR * 4096 + (size_t)(idx * 64 + l) * 8, &Rs[idx * 512]);
  }
#pragma unroll
  for (int i = 0; i < 4; ++i) {
    const int idx = w * 4 + i;
    gload16(hp_sw + (size_t)(b * 32 + (idx >> 3)) * 4096 + (size_t)((idx & 7) * 64 + l) * 8,
            &Cs[0][idx * 512]);
  }
  __syncthreads();
  const bf16x8 bq0 = *(const bf16x8*)&Rs[((lg)*64 + (w << 4) + lr) * 8];
  const bf16x8 bq1 = *(const bf16x8*)&Rs[((lg + 4) * 64 + (w << 4) + lr) * 8];
  float S = 0.f;
  for (int mt = 0; mt < 16; ++mt) {
    const int cur = mt & 1;
    if (mt + 1 < 16) {
#pragma unroll
      for (int i = 0; i < 4; ++i) {
        const int idx = w * 4 + i;
        gload16(hp_sw + (size_t)(b * 32 + (mt + 1) * 2 + (idx >> 3)) * 4096 +
                    (size_t)((idx & 7) * 64 + l) * 8,
                &Cs[cur ^ 1][idx * 512]);
      }
    }
#pragma unroll
    for (int mf = 0; mf < 8; ++mf) {
      const int toff = (mf >> 2) * 4096;
      const int mloc = (mf & 3) * 16;
      const bf16x8 a0 = *(const bf16x8*)&Cs[cur][toff + ((lg)*64 + mloc + lr) * 8];
      const bf16x8 a1 = *(const bf16x8*)&Cs[cur][toff + ((lg + 4) * 64 + mloc + lr) * 8];
      f32x4 z;
      z[0] = 0.f; z[1] = 0.f; z[2] = 0.f; z[3] = 0.f;
      z = mfma16(a0, bq0, z);
      z = mfma16(a1, bq1, z);
      S += __expf(lrelu(z[0]) - 30.f) + __expf(lrelu(z[1]) - 30.f) +
           __expf(lrelu(z[2]) - 30.f) + __expf(lrelu(z[3]) - 30.f);
    }
    __syncthreads();
  }
  S += __shfl_xor(S, 16);
  S += __shfl_xor(S, 32);
  if (l < 16) iDbuf[b * NN + n0 + (w << 4) + l] = 1.f / S;
}

// ---------------- K_attnB: S[n] = sum_m exp(e[n,m]-30)/D[m]; out = hp * S ----
__global__ __launch_bounds__(256) void k_attnB(const u16* __restrict__ hp_sw,
                                               const float* __restrict__ iDbuf,
                                               float* __restrict__ out) {
  const int b = blockIdx.x >> 5;
  const int n0 = (blockIdx.x & 31) << 6;
  const int t = threadIdx.x, w = t >> 6, l = t & 63;
  const int lg = l >> 4, lr = l & 15;
  __shared__ __align__(16) u16 Rs[4096];
  __shared__ __align__(16) u16 Cs[2][8192];
  __shared__ __align__(16) float Dv[2][128];
  __shared__ float Sv[64];
  const int tileR = b * 32 + (n0 >> 6);
#pragma unroll
  for (int i = 0; i < 2; ++i) {
    const int idx = w * 2 + i;
    gload16(hp_sw + (size_t)tileR * 4096 + (size_t)(idx * 64 + l) * 8, &Rs[idx * 512]);
  }
#pragma unroll
  for (int i = 0; i < 4; ++i) {
    const int idx = w * 4 + i;
    gload16(hp_sw + (size_t)(b * 32 + (idx >> 3)) * 4096 + (size_t)((idx & 7) * 64 + l) * 8,
            &Cs[0][idx * 512]);
  }
  if (t < 128) Dv[0][t] = iDbuf[b * NN + t];
  __syncthreads();
  const bf16x8 bq0 = *(const bf16x8*)&Rs[((lg)*64 + (w << 4) + lr) * 8];
  const bf16x8 bq1 = *(const bf16x8*)&Rs[((lg + 4) * 64 + (w << 4) + lr) * 8];
  float S = 0.f;
  for (int mt = 0; mt < 16; ++mt) {
    const int cur = mt & 1;
    if (mt + 1 < 16) {
#pragma unroll
      for (int i = 0; i < 4; ++i) {
        const int idx = w * 4 + i;
        gload16(hp_sw + (size_t)(b * 32 + (mt + 1) * 2 + (idx >> 3)) * 4096 +
                    (size_t)((idx & 7) * 64 + l) * 8,
                &Cs[cur ^ 1][idx * 512]);
      }
      if (t < 128) Dv[cur ^ 1][t] = iDbuf[b * NN + (mt + 1) * 128 + t];
    }
#pragma unroll
    for (int mf = 0; mf < 8; ++mf) {
      const int toff = (mf >> 2) * 4096;
      const int mloc = (mf & 3) * 16;
      const bf16x8 a0 = *(const bf16x8*)&Cs[cur][toff + ((lg)*64 + mloc + lr) * 8];
      const bf16x8 a1 = *(const bf16x8*)&Cs[cur][toff + ((lg + 4) * 64 + mloc + lr) * 8];
      f32x4 z;
      z[0] = 0.f; z[1] = 0.f; z[2] = 0.f; z[3] = 0.f;
      z = mfma16(a0, bq0, z);
      z = mfma16(a1, bq1, z);
      const float4 dv = *(const float4*)&Dv[cur][(mf >> 2) * 64 + (mf & 3) * 16 + lg * 4];
      S += __expf(lrelu(z[0]) - 30.f) * dv.x;
      S += __expf(lrelu(z[1]) - 30.f) * dv.y;
      S += __expf(lrelu(z[2]) - 30.f) * dv.z;
      S += __expf(lrelu(z[3]) - 30.f) * dv.w;
    }
    __syncthreads();
  }
  S += __shfl_xor(S, 16);
  S += __shfl_xor(S, 32);
  if (l < 16) Sv[(w << 4) + l] = S;
  __syncthreads();
  const int row = t >> 2;
  const float sc = Sv[row];
  const size_t R = (size_t)b * NN + n0 + row;
#pragma unroll
  for (int hh = 0; hh < 2; ++hh) {
    const int kb = (t & 3) * 2 + hh;
    const u16* src = &Rs[(kb * 64 + row) * 8];
    float4 o0, o1;
    o0.x = bf2f(src[0]) * sc;
    o0.y = bf2f(src[1]) * sc;
    o0.z = bf2f(src[2]) * sc;
    o0.w = bf2f(src[3]) * sc;
    o1.x = bf2f(src[4]) * sc;
    o1.y = bf2f(src[5]) * sc;
    o1.z = bf2f(src[6]) * sc;
    o1.w = bf2f(src[7]) * sc;
    *(float4*)&out[R * NO + kb * 8] = o0;
    *(float4*)&out[R * NO + kb * 8 + 4] = o1;
  }
}

extern "C" void kernel_launch(void* const* d_in, const int* in_sizes, int n_in,
                              void* d_out, int out_size, void* d_ws, size_t ws_size,
                              hipStream_t stream) {
  const float* x = (const float*)d_in[0];
  // d_in[1] = adj (unused)
  const float* adj_gcn = (const float*)d_in[2];
  const float* gcn_w = (const float*)d_in[3];
  const float* gcn_b = (const float*)d_in[4];
  const float* gamma = (const float*)d_in[5];
  const float* beta = (const float*)d_in[6];
  const float* gat_w = (const float*)d_in[7];
  float* out = (float*)d_out;
  float* ws = (float*)d_ws;

  // workspace layout (float units), peak ~9.62M floats (38.5MB):
  u16* adj_sw = (u16*)ws;                  // [0, 2M) floats
  u16* suppT_sw = (u16*)(ws + 2097152);    // [2M, 4M)
  float* hbuf = ws + 4194304;              // [4M, 8M)
  u16* x_sw = (u16*)(ws + 4194304);        // aliases hbuf lower half (dead first)
  u16* hp_sw = (u16*)(ws + 8388608);       // [8M, 9M)
  float* iDbuf = ws + 9437184;             // 32768
  float* psum = iDbuf + 32768;             // 65536
  float* psq = psum + 65536;               // 65536
  float* scale = psq + 65536;              // 128
  float* shift = scale + 128;              // 128
  float* gWT = shift + 128;                // 8192
  u16* Wsw = (u16*)(gWT + 8192);           // 16384 u16

  k_prep<<<dim3(1289), dim3(256), 0, stream>>>(x, adj_gcn, gcn_w, gat_w, x_sw, adj_sw, gWT, Wsw);
  k_support<<<dim3(256), dim3(256), 0, stream>>>(x_sw, Wsw, suppT_sw);
  k_gcn<<<dim3(32, 16), dim3(256), 0, stream>>>(adj_sw, suppT_sw, gcn_b, hbuf, psum, psq);
  k_bnstat2<<<dim3(1), dim3(1024), 0, stream>>>(psum, psq, gamma, beta, scale, shift);
  k_hp<<<dim3(512), dim3(256), 0, stream>>>(hbuf, scale, shift, gWT, hp_sw);
  k_attnA<<<dim3(NB * 32), dim3(256), 0, stream>>>(hp_sw, iDbuf);
  k_attnB<<<dim3(NB * 32), dim3(256), 0, stream>>>(hp_sw, iDbuf, out);
}